// Round 1
// baseline (653.271 us; speedup 1.0000x reference)
//
#include <hip/hip_runtime.h>

typedef unsigned short u16;
typedef unsigned int u32;
using f32x4 = __attribute__((ext_vector_type(4))) float;
using bf16x8 = __attribute__((ext_vector_type(8))) __bf16;

constexpr int Bc = 4, Tc = 2048, Dc = 2048, Hc = 16, Gc = 4, Kc = 128;
constexpr float EPSc = 1e-6f;

__device__ __forceinline__ u16 f2bf(float f) {
    u32 u = __float_as_uint(f);
    u = (u + 0x7fffu + ((u >> 16) & 1u)) >> 16;
    return (u16)u;
}
__device__ __forceinline__ float bf2f(u16 h) {
    return __uint_as_float(((u32)h) << 16);
}

// ---------------- fp32 -> bf16 convert ----------------
__global__ __launch_bounds__(256) void cvt_f2bf(const float* __restrict__ in,
                                                u16* __restrict__ out, int n) {
    int i = (blockIdx.x * 256 + threadIdx.x) * 4;
    if (i >= n) return;
    float4 f = *(const float4*)(in + i);
    u16 r[4] = { f2bf(f.x), f2bf(f.y), f2bf(f.z), f2bf(f.w) };
    *(uint2*)(out + i) = *(uint2*)r;
}

// ------- transpose+convert: in (rows x cols) f32 -> out (cols x rows) bf16 -------
__global__ __launch_bounds__(256) void transpose_f2bf(const float* __restrict__ in,
                                                      u16* __restrict__ out,
                                                      int rows, int cols) {
    __shared__ float tile[32][33];
    int tx = threadIdx.x & 31, ty = threadIdx.x >> 5;
    int c0 = blockIdx.x * 32, r0 = blockIdx.y * 32;
#pragma unroll
    for (int j = 0; j < 4; j++)
        tile[ty + j * 8][tx] = in[(size_t)(r0 + ty + j * 8) * cols + c0 + tx];
    __syncthreads();
#pragma unroll
    for (int j = 0; j < 4; j++)
        out[(size_t)(c0 + ty + j * 8) * rows + r0 + tx] = f2bf(tile[tx][ty + j * 8]);
}

// ---------------- positions from (sorted) segment ids ----------------
__global__ void pos_kernel(const int* __restrict__ seg, int* __restrict__ pos) {
    int idx = blockIdx.x * 256 + threadIdx.x;
    if (idx >= Bc * Tc) return;
    int b = idx / Tc, t = idx - b * Tc;
    const int* s = seg + b * Tc;
    int v = s[t];
    int lo = 0, hi = t;
    while (lo < hi) { int mid = (lo + hi) >> 1; if (s[mid] < v) lo = mid + 1; else hi = mid; }
    pos[idx] = t - lo;   // t - seg_start
}

// ---------------- bf16 GEMM: C(MxN) = A(MxKd) * Bt(NxKd)^T ----------------
#define GBM 128
#define GBN 128
#define GBK 32
#define LSTR 40   // padded LDS row stride (u16) -> breaks pow2 bank aliasing, keeps 16B align

__global__ __launch_bounds__(256) void gemm_bt(const u16* __restrict__ A,
                                               const u16* __restrict__ Bt,
                                               float* __restrict__ Cf, u16* __restrict__ Cb,
                                               int M, int N, int Kd) {
    __shared__ u16 lA[GBM * LSTR];
    __shared__ u16 lB[GBN * LSTR];
    const int tid = threadIdx.x;
    const int m0 = blockIdx.y * GBM, n0 = blockIdx.x * GBN;
    const int wave = tid >> 6, lane = tid & 63;
    const int l16 = lane & 15, quad = lane >> 4;
    const int wm = (wave & 1) * 64, wn = (wave >> 1) * 64;

    const int c0 = tid, c1 = tid + 256;           // 16B chunks: row=c>>2, kchunk=(c&3)*8
    const u16* gA0 = A + (size_t)(m0 + (c0 >> 2)) * Kd + (c0 & 3) * 8;
    const u16* gA1 = A + (size_t)(m0 + (c1 >> 2)) * Kd + (c1 & 3) * 8;
    const u16* gB0 = Bt + (size_t)(n0 + (c0 >> 2)) * Kd + (c0 & 3) * 8;
    const u16* gB1 = Bt + (size_t)(n0 + (c1 >> 2)) * Kd + (c1 & 3) * 8;
    u16* sA0 = &lA[(c0 >> 2) * LSTR + (c0 & 3) * 8];
    u16* sA1 = &lA[(c1 >> 2) * LSTR + (c1 & 3) * 8];
    u16* sB0 = &lB[(c0 >> 2) * LSTR + (c0 & 3) * 8];
    u16* sB1 = &lB[(c1 >> 2) * LSTR + (c1 & 3) * 8];

    const f32x4 fz = {0.f, 0.f, 0.f, 0.f};
    f32x4 acc[4][4];
#pragma unroll
    for (int i = 0; i < 4; i++)
#pragma unroll
        for (int j = 0; j < 4; j++) acc[i][j] = fz;

    for (int k0 = 0; k0 < Kd; k0 += GBK) {
        uint4 ra0 = *(const uint4*)(gA0 + k0);   // prefetch to regs (overlaps prev compute)
        uint4 ra1 = *(const uint4*)(gA1 + k0);
        uint4 rb0 = *(const uint4*)(gB0 + k0);
        uint4 rb1 = *(const uint4*)(gB1 + k0);
        __syncthreads();                          // prev iter LDS reads done
        *(uint4*)sA0 = ra0;
        *(uint4*)sA1 = ra1;
        *(uint4*)sB0 = rb0;
        *(uint4*)sB1 = rb1;
        __syncthreads();                          // staging visible
        bf16x8 af[4], bg[4];
#pragma unroll
        for (int i = 0; i < 4; i++) {
            af[i] = *(const bf16x8*)&lA[(wm + i * 16 + l16) * LSTR + quad * 8];
            bg[i] = *(const bf16x8*)&lB[(wn + i * 16 + l16) * LSTR + quad * 8];
        }
#pragma unroll
        for (int mi = 0; mi < 4; mi++)
#pragma unroll
            for (int ni = 0; ni < 4; ni++)
                acc[mi][ni] = __builtin_amdgcn_mfma_f32_16x16x32_bf16(af[mi], bg[ni], acc[mi][ni], 0, 0, 0);
    }

#pragma unroll
    for (int mi = 0; mi < 4; mi++)
#pragma unroll
        for (int ni = 0; ni < 4; ni++)
#pragma unroll
            for (int r = 0; r < 4; r++) {
                int row = m0 + wm + mi * 16 + quad * 4 + r;   // C/D: row=quad*4+reg
                int col = n0 + wn + ni * 16 + l16;            //      col=lane&15
                float v = acc[mi][ni][r];
                if (Cf) Cf[(size_t)row * N + col] = v;
                else    Cb[(size_t)row * N + col] = f2bf(v);
            }
}

// ---------------- fused RMSNorm + RoPE, in place on bf16 rows of 128 ----------------
__global__ __launch_bounds__(256) void rms_rope(u16* __restrict__ X,
                                                const float* __restrict__ sc,
                                                const int* __restrict__ pos, int NH) {
    int row = blockIdx.x * 4 + (threadIdx.x >> 6);   // one wave per (b,t,head) row
    int lane = threadIdx.x & 63;
    int bt = row / NH;
    u16* xp = X + (size_t)row * Kc;
    float x1 = bf2f(xp[lane]), x2 = bf2f(xp[lane + 64]);   // rope pairs (j, j+64)
    float ss = x1 * x1 + x2 * x2;
#pragma unroll
    for (int m = 1; m < 64; m <<= 1) ss += __shfl_xor(ss, m, 64);
    float rn = rsqrtf(ss * (1.f / 128.f) + EPSc);
    float y1 = x1 * rn * sc[lane];
    float y2 = x2 * rn * sc[lane + 64];
    float inv_freq = expf(-logf(10000.f) * ((float)(2 * lane) * (1.f / 128.f)));
    float ang = (float)pos[bt] * inv_freq;
    float sv, cv;
    sincosf(ang, &sv, &cv);
    xp[lane]      = f2bf(y1 * cv - y2 * sv);
    xp[lane + 64] = f2bf(y2 * cv + y1 * sv);
}

// ---------------- flash attention: 64 q-rows per block, 64-wide s-tiles ----------------
#define QSTR 136   // 128+8, keeps 16B align, bank-decorrelated
#define VSTR 80    // 64+16
#define PSTR 80

__global__ __launch_bounds__(256) void flash_attn(const u16* __restrict__ Qb,
                                                  const u16* __restrict__ Kb,
                                                  const u16* __restrict__ Vb,
                                                  const int* __restrict__ seg,
                                                  const int* __restrict__ pos,
                                                  u16* __restrict__ Ob) {
    __shared__ u16 lQ[64 * QSTR];
    __shared__ u16 lK[64 * QSTR];
    __shared__ u16 lVt[128 * VSTR];   // V transposed: [d][s]
    __shared__ u16 lP[64 * PSTR];

    const int b = blockIdx.z, h = blockIdx.y, g = h >> 2;   // g = h / R, R=4
    const int q0 = blockIdx.x * 64;
    const int tid = threadIdx.x;
    const int wave = tid >> 6, lane = tid & 63;
    const int l16 = lane & 15, quad = lane >> 4;
    const float scale = 0.08838834764831845f;   // K^-0.5

    // stage Q tile (64 x 128)
#pragma unroll
    for (int it = 0; it < 4; it++) {
        int c = tid + it * 256;
        int r = c >> 4, dc = (c & 15) * 8;
        *(uint4*)&lQ[r * QSTR + dc] =
            *(const uint4*)&Qb[((size_t)(b * Tc + q0 + r) * Hc + h) * Kc + dc];
    }

    int tg[4], sgt[4];
#pragma unroll
    for (int r = 0; r < 4; r++) {
        tg[r] = q0 + wave * 16 + quad * 4 + r;
        sgt[r] = seg[b * Tc + tg[r]];
    }

    float m_i[4], l_i[4];
#pragma unroll
    for (int r = 0; r < 4; r++) { m_i[r] = -1e30f; l_i[r] = 0.f; }
    const f32x4 fz = {0.f, 0.f, 0.f, 0.f};
    f32x4 oc[8];
#pragma unroll
    for (int i = 0; i < 8; i++) oc[i] = fz;

    // segments sorted => valid s range is [seg_start(q0), q-tile end]
    const int s_begin = ((q0 - pos[b * Tc + q0]) >> 6) << 6;

    for (int s0 = s_begin; s0 <= q0; s0 += 64) {
        __syncthreads();   // prior K/V/P reads complete before restage
        // stage K tile (64 x 128)
#pragma unroll
        for (int it = 0; it < 4; it++) {
            int c = tid + it * 256;
            int r = c >> 4, dc = (c & 15) * 8;
            *(uint4*)&lK[r * QSTR + dc] =
                *(const uint4*)&Kb[((size_t)(b * Tc + s0 + r) * Gc + g) * Kc + dc];
        }
        // stage V transposed (conflict-free LDS writes; gathered global reads hit L2)
#pragma unroll
        for (int it = 0; it < 4; it++) {
            int c = tid + it * 256;
            int s = c & 63, dg = c >> 6;
            int dc = dg * 8;
            uint4 w4 = *(const uint4*)&Vb[((size_t)(b * Tc + s0 + s) * Gc + g) * Kc + dc];
            u16 tmp[8];
            *(uint4*)tmp = w4;
#pragma unroll
            for (int j = 0; j < 8; j++) lVt[(dc + j) * VSTR + s] = tmp[j];
        }
        __syncthreads();

        // S = Q K^T : per-wave 16 rows x 64 cols
        f32x4 sacc[4];
#pragma unroll
        for (int nj = 0; nj < 4; nj++) sacc[nj] = fz;
#pragma unroll
        for (int kk = 0; kk < 4; kk++) {
            bf16x8 aq = *(const bf16x8*)&lQ[(wave * 16 + l16) * QSTR + kk * 32 + quad * 8];
#pragma unroll
            for (int nj = 0; nj < 4; nj++) {
                bf16x8 bk = *(const bf16x8*)&lK[(nj * 16 + l16) * QSTR + kk * 32 + quad * 8];
                sacc[nj] = __builtin_amdgcn_mfma_f32_16x16x32_bf16(aq, bk, sacc[nj], 0, 0, 0);
            }
        }

        int sgs[4];
#pragma unroll
        for (int nj = 0; nj < 4; nj++) sgs[nj] = seg[b * Tc + s0 + nj * 16 + l16];

        // mask + online softmax (lane holds rows quad*4+r, cols nj*16+l16)
        float xv[4][4], rmax[4];
#pragma unroll
        for (int r = 0; r < 4; r++) rmax[r] = -1e30f;
#pragma unroll
        for (int nj = 0; nj < 4; nj++) {
            int sIdx = s0 + nj * 16 + l16;
#pragma unroll
            for (int r = 0; r < 4; r++) {
                bool ok = (sIdx <= tg[r]) && (sgs[nj] == sgt[r]);
                float x = ok ? sacc[nj][r] * scale : -1e30f;
                xv[nj][r] = x;
                rmax[r] = fmaxf(rmax[r], x);
            }
        }
#pragma unroll
        for (int r = 0; r < 4; r++) {
            float v = rmax[r];
            v = fmaxf(v, __shfl_xor(v, 1, 64));
            v = fmaxf(v, __shfl_xor(v, 2, 64));
            v = fmaxf(v, __shfl_xor(v, 4, 64));
            v = fmaxf(v, __shfl_xor(v, 8, 64));
            rmax[r] = v;
        }
        float alpha[4];
#pragma unroll
        for (int r = 0; r < 4; r++) {
            float mnew = fmaxf(m_i[r], rmax[r]);
            alpha[r] = __expf(m_i[r] - mnew);   // both >= -1e30 finite: no NaN
            m_i[r] = mnew;
        }
        float psum[4] = {0.f, 0.f, 0.f, 0.f};
#pragma unroll
        for (int nj = 0; nj < 4; nj++) {
#pragma unroll
            for (int r = 0; r < 4; r++) {
                float x = xv[nj][r];
                float p = (x > -1e29f) ? __expf(x - m_i[r]) : 0.f;   // masked -> exactly 0
                psum[r] += p;
                lP[(wave * 16 + quad * 4 + r) * PSTR + nj * 16 + l16] = f2bf(p);
            }
        }
#pragma unroll
        for (int r = 0; r < 4; r++) {
            float v = psum[r];
            v += __shfl_xor(v, 1, 64);
            v += __shfl_xor(v, 2, 64);
            v += __shfl_xor(v, 4, 64);
            v += __shfl_xor(v, 8, 64);
            l_i[r] = l_i[r] * alpha[r] + v;
        }
#pragma unroll
        for (int ni = 0; ni < 8; ni++)
#pragma unroll
            for (int r = 0; r < 4; r++) oc[ni][r] *= alpha[r];

        __syncthreads();   // lP C-layout writes -> A-layout reads

        // O += P V  (K=64 over s, N=128 over head dim)
#pragma unroll
        for (int kk = 0; kk < 2; kk++) {
            bf16x8 ap = *(const bf16x8*)&lP[(wave * 16 + l16) * PSTR + kk * 32 + quad * 8];
#pragma unroll
            for (int ni = 0; ni < 8; ni++) {
                bf16x8 bv = *(const bf16x8*)&lVt[(ni * 16 + l16) * VSTR + kk * 32 + quad * 8];
                oc[ni] = __builtin_amdgcn_mfma_f32_16x16x32_bf16(ap, bv, oc[ni], 0, 0, 0);
            }
        }
    }

    float invl[4];
#pragma unroll
    for (int r = 0; r < 4; r++) invl[r] = 1.f / l_i[r];
#pragma unroll
    for (int ni = 0; ni < 8; ni++)
#pragma unroll
        for (int r = 0; r < 4; r++) {
            size_t oi = ((size_t)(b * Tc + q0 + wave * 16 + quad * 4 + r) * Hc + h) * Kc + ni * 16 + l16;
            Ob[oi] = f2bf(oc[ni][r] * invl[r]);
        }
}

extern "C" void kernel_launch(void* const* d_in, const int* in_sizes, int n_in,
                              void* d_out, int out_size, void* d_ws, size_t ws_size,
                              hipStream_t stream) {
    const float* hidden  = (const float*)d_in[0];
    const float* wq      = (const float*)d_in[1];
    const float* wk      = (const float*)d_in[2];
    const float* wv      = (const float*)d_in[3];
    const float* wo      = (const float*)d_in[4];
    const float* q_scale = (const float*)d_in[5];
    const float* k_scale = (const float*)d_in[6];
    const int*   segids  = (const int*)d_in[7];
    float* out = (float*)d_out;

    char* ws = (char*)d_ws;
    size_t off = 0;
    auto alloc = [&](size_t bytes) -> void* {
        void* p = ws + off;
        off += (bytes + 255) & ~(size_t)255;
        return p;
    };
    u16* hbf  = (u16*)alloc((size_t)Bc * Tc * Dc * 2);        // hidden bf16
    u16* wqT  = (u16*)alloc((size_t)Hc * Kc * Dc * 2);        // (2048 x 2048)
    u16* wkT  = (u16*)alloc((size_t)Gc * Kc * Dc * 2);        // (512 x 2048)
    u16* wvT  = (u16*)alloc((size_t)Gc * Kc * Dc * 2);
    u16* woT  = (u16*)alloc((size_t)Dc * Hc * Kc * 2);        // (2048 x 2048)
    u16* qb   = (u16*)alloc((size_t)Bc * Tc * Hc * Kc * 2);
    u16* kb   = (u16*)alloc((size_t)Bc * Tc * Gc * Kc * 2);
    u16* vb   = (u16*)alloc((size_t)Bc * Tc * Gc * Kc * 2);
    u16* attn = (u16*)alloc((size_t)Bc * Tc * Hc * Kc * 2);
    int* posb = (int*)alloc((size_t)Bc * Tc * 4);
    (void)ws_size; (void)in_sizes; (void)n_in; (void)out_size;

    const int M = Bc * Tc;   // 8192

    cvt_f2bf<<<(Bc * Tc * Dc) / 1024, 256, 0, stream>>>(hidden, hbf, Bc * Tc * Dc);
    transpose_f2bf<<<dim3(64, 64), 256, 0, stream>>>(wq, wqT, Dc, Hc * Kc);
    transpose_f2bf<<<dim3(16, 64), 256, 0, stream>>>(wk, wkT, Dc, Gc * Kc);
    transpose_f2bf<<<dim3(16, 64), 256, 0, stream>>>(wv, wvT, Dc, Gc * Kc);
    transpose_f2bf<<<dim3(64, 64), 256, 0, stream>>>(wo, woT, Hc * Kc, Dc);
    pos_kernel<<<(Bc * Tc) / 256, 256, 0, stream>>>(segids, posb);

    gemm_bt<<<dim3((Hc * Kc) / GBN, M / GBM), 256, 0, stream>>>(hbf, wqT, nullptr, qb, M, Hc * Kc, Dc);
    gemm_bt<<<dim3((Gc * Kc) / GBN, M / GBM), 256, 0, stream>>>(hbf, wkT, nullptr, kb, M, Gc * Kc, Dc);
    gemm_bt<<<dim3((Gc * Kc) / GBN, M / GBM), 256, 0, stream>>>(hbf, wvT, nullptr, vb, M, Gc * Kc, Dc);

    rms_rope<<<(M * Hc) / 4, 256, 0, stream>>>(qb, q_scale, posb, Hc);
    rms_rope<<<(M * Gc) / 4, 256, 0, stream>>>(kb, k_scale, posb, Gc);

    flash_attn<<<dim3(Tc / 64, Hc, Bc), 256, 0, stream>>>(qb, kb, vb, segids, posb, attn);

    gemm_bt<<<dim3(Dc / GBN, M / GBM), 256, 0, stream>>>(attn, woT, out, nullptr, M, Dc, Hc * Kc);
}